// Round 5
// baseline (316.775 us; speedup 1.0000x reference)
//
#include <hip/hip_runtime.h>

#define S_LEN 4096
#define NBATCH 2
#define OUT_ELEMS 2097152            // B*2*S*H

typedef _Float16 f16;
typedef _Float16 f16x8 __attribute__((ext_vector_type(8)));
typedef _Float16 f16x4 __attribute__((ext_vector_type(4)));
typedef float f32x4 __attribute__((ext_vector_type(4)));

// ---- workspace layout (bytes) ----
#define MT_OFF    0x000000   // 4 x 256x256 f16 (transposed M matrices)  512 KB
#define BIAS_OFF  0x080000   // 4 x 256 f32
#define SC_OFF    0x081000   // scalars: kc, nf2
#define QH_OFF    0x100000   // 8192x256 f16   4 MB
#define KH_OFF    0x500000   // 8192x256 f16   4 MB
#define VH_OFF    0x900000   // 8192x256 f16 (row-major V)   4 MB
#define Q2_OFF    0xD00000   // 8192 f32 (q2, k2, lsum share a 192KB zeroed region)
#define K2_OFF    0xD10000
#define L_OFF     0xD20000
#define VPT_OFF   0xE00000   // [b][256][4096] f16 = (V@Mp)^T   4 MB
#define PW_OFF    0x1600000  // [b][4096][4096] f16 unnormalized P   64 MB
#define WS_NEED   0x5600000

#define MFMA16(A,B,C) __builtin_amdgcn_mfma_f32_16x16x32_f16(A,B,C,0,0,0)

__device__ __forceinline__ void async_cp16(f16* lds, const f16* g) {
  __builtin_amdgcn_global_load_lds(
      (const __attribute__((address_space(1))) void*)g,
      (__attribute__((address_space(3))) void*)lds, 16, 0, 0);
}

// T2 swizzle: logical 16B-chunk s of row r lives at LDS chunk s ^ ((r>>1)&3).
// Staging keeps LDS dest linear (global_load_lds requirement) and applies the
// inverse permutation on the global source; reads apply the same XOR.

// stage 128x32 f16 tile (global row stride = stride elems) -> lds[128][32] swizzled
__device__ __forceinline__ void stage16(f16* lds, const f16* g, int stride, int tid) {
#pragma unroll
  for (int i = 0; i < 2; ++i) {
    int idx = i*256 + tid;
    int row = idx >> 2, c = idx & 3;
    int cs = c ^ ((row >> 1) & 3);
    async_cp16(lds + idx*8, g + (size_t)row*stride + cs*8);
  }
}

// stage 128x32 f32 tile -> f16 lds[128][32] (convert), swizzled LDS write
__device__ __forceinline__ void stage32(f16* lds, const float* g, int stride, int tid) {
#pragma unroll
  for (int i = 0; i < 4; ++i) {
    int idx = i*256 + tid;
    int row = idx >> 3, c = idx & 7;           // c: 8B units
    const float4* gp = (const float4*)(g + (size_t)row*stride + c*4);
    float4 v = *gp;
    f16x4 h; h[0]=(f16)v.x; h[1]=(f16)v.y; h[2]=(f16)v.z; h[3]=(f16)v.w;
    int cl = (((c >> 1) ^ ((row >> 1) & 3)) << 1) | (c & 1);
    *(f16x4*)(lds + row*32 + cl*4) = h;
  }
}

// one BK=32 step: 4 A-frags, 4 B-frags, 16 MFMAs (wave covers 64x64 of 128x128)
__device__ __forceinline__ void mfma_step(const f16* Asm, const f16* Bsm, int lane,
                                          int wm, int wn, f32x4 acc[4][4]) {
  f16x8 a[4], b[4];
  int rr = lane & 15;
  int sc = (lane >> 4) ^ ((rr >> 1) & 3);   // swizzled 16B chunk index
#pragma unroll
  for (int i=0;i<4;i++) a[i] = *(const f16x8*)(Asm + (wm + i*16 + rr)*32 + (sc<<3));
#pragma unroll
  for (int j=0;j<4;j++) b[j] = *(const f16x8*)(Bsm + (wn + j*16 + rr)*32 + (sc<<3));
#pragma unroll
  for (int i=0;i<4;i++)
#pragma unroll
    for (int j=0;j<4;j++) acc[i][j] = MFMA16(a[i], b[j], acc[i][j]);
}

// ---- build combined complex-linear matrices Mt[n][k] = M[k][n], and biases ----
__global__ __launch_bounds__(256)
void k_build(const float* Wqr, const float* Wqi, const float* bqr, const float* bqi,
             const float* Wkr, const float* Wki, const float* bkr, const float* bki,
             const float* Wvr, const float* Wvi, const float* bvr, const float* bvi,
             const float* Wpr, const float* Wpi, const float* bpr, const float* bpi,
             f16* Mt, float* bias) {
  int mat = blockIdx.x;
  const float *Wr, *Wi, *br, *bi;
  if (mat == 0)      { Wr=Wqr; Wi=Wqi; br=bqr; bi=bqi; }
  else if (mat == 1) { Wr=Wkr; Wi=Wki; br=bkr; bi=bki; }
  else if (mat == 2) { Wr=Wvr; Wi=Wvi; br=bvr; bi=bvi; }
  else               { Wr=Wpr; Wi=Wpi; br=bpr; bi=bpi; }
  int idx = blockIdx.y*256 + threadIdx.x;
  int n = idx >> 8, k = idx & 255;
  int d = k & 127, h = n & 127;
  float w = (k < 128) ? ((n < 128) ? Wr[h*128+d] : Wi[h*128+d])
                      : ((n < 128) ? -Wi[h*128+d] : Wr[h*128+d]);
  Mt[mat*65536 + n*256 + k] = (f16)w;
  if (k == 0)
    bias[mat*256 + n] = (n < 128) ? (br[n] - bi[n]) : (br[n-128] + bi[n-128]);
}

// ---- init: coalesced zero of strictly-upper attn tiles (992 blocks);
//      prefill out with bias; zero q2/k2/lsum; compute scalars ----
__global__ __launch_bounds__(256)
void k_init(float* outp, float* attn, float* zreg, float* sc, const float* bias,
            const float* nf, const float* tau) {
  int bx = blockIdx.x, tid = threadIdx.x;
  float4 z = make_float4(0.f,0.f,0.f,0.f);
  if (bx < 992) {              // one strictly-upper 128x128 tile, coalesced
    int b = bx >= 496; int r = bx - b*496;
    int tb = 1; while (r >= tb) { r -= tb; tb++; }
    int sb = r;
    float* base = attn + ((size_t)(b*S_LEN) + sb*128)*S_LEN + tb*128;
    int c4 = tid & 31;
#pragma unroll
    for (int it = 0; it < 16; ++it) {
      int row = it*8 + (tid >> 5);
      *(float4*)(base + (size_t)row*S_LEN + c4*4) = z;
    }
    return;
  }
  int idx = (bx - 992)*256 + tid;
  if (idx < 524288) {          // out prefill with bias (524288 float4 = 8.4 MB)
    int h4 = idx & 31;
    int comp = (idx >> 17) & 1;
    ((float4*)outp)[idx] = *(const float4*)(bias + 3*256 + comp*128 + h4*4);
  } else {
    int j = idx - 524288;
    if (j < 12288) ((float4*)zreg)[j] = z;
  }
  if (idx == 0) {
    float t = tau[0];
    float c = __builtin_log2f(1.0f + __builtin_exp2f(t * 1.4426950408889634f))
              * 0.6931471805599453f;        // softplus(tau)
    sc[0] = -c * 0.08838834764831845f;       // kc = -softplus(tau)/sqrt(128)
    sc[1] = nf[0]*nf[0] + 1e-6f;             // nf^2 + EPS
  }
}

// ---- projections + fused |row|^2 for Q/K (squares of the f16-rounded values) ----
__global__ __launch_bounds__(256)
void k_proj(const float* Zq, const float* Zk, const float* Zv,
            const f16* Mt, const float* bias,
            f16* Qh, f16* Kh, f16* Vh, float* q2, float* k2) {
  __shared__ f16 Asm[2][128*32];
  __shared__ f16 Bsm[2][128*32];
  __shared__ float bias_s[128];
  int tid = threadIdx.x;
  int mode = blockIdx.z;
  int m0 = blockIdx.x * 128, n0 = blockIdx.y * 128;
  const float* Z = (mode==0) ? Zq : (mode==1 ? Zk : Zv);
  const f16* Bt = Mt + mode*65536;
  if (tid < 128) bias_s[tid] = bias[mode*256 + n0 + tid];
  int b = m0 >> 12, s0 = m0 & 4095;
  int lane = tid & 63, w = tid >> 6;
  int wm = (w >> 1)*64, wn = (w & 1)*64;
  f32x4 acc[4][4] = {};
  // prologue: stage k-step 0
  {
    const float* Ag = Z + (((size_t)(b*2 + 0))*S_LEN + s0)*128 + 0;
    stage32(Asm[0], Ag, 128, tid);
    stage16(Bsm[0], Bt + n0*256 + 0, 256, tid);
  }
  __syncthreads();
  for (int kb = 0; kb < 8; ++kb) {
    int cur = kb & 1;
    if (kb < 7) {
      int k1 = (kb+1)*32;
      int part = k1 >> 7, d0 = k1 & 127;
      const float* Ag = Z + (((size_t)(b*2 + part))*S_LEN + s0)*128 + d0;
      stage32(Asm[cur^1], Ag, 128, tid);
      stage16(Bsm[cur^1], Bt + n0*256 + k1, 256, tid);
    }
    mfma_step(Asm[cur], Bsm[cur], lane, wm, wn, acc);
    __syncthreads();
  }
  int rr = (lane>>4)*4, cc = lane & 15;
  f16* O = (mode==0) ? Qh : (mode==1 ? Kh : Vh);
  float rs[4][4];
#pragma unroll
  for (int i=0;i<4;i++)
#pragma unroll
    for (int r=0;r<4;r++) rs[i][r]=0.f;
#pragma unroll
  for (int i=0;i<4;i++)
#pragma unroll
    for (int j=0;j<4;j++) {
      int cl = wn + j*16 + cc;
      int cg = n0 + cl;
      float bv = bias_s[cl];
#pragma unroll
      for (int r=0;r<4;r++) {
        int rg = m0 + wm + i*16 + rr + r;
        f16 hv = (f16)(acc[i][j][r] + bv);
        O[(size_t)rg*256 + cg] = hv;
        float fv = (float)hv;
        rs[i][r] += fv*fv;
      }
    }
  if (mode < 2) {
    // reduce across cc lanes (bits 0..3) and atomically add the half-row sums
#pragma unroll
    for (int m=8;m>=1;m>>=1)
#pragma unroll
      for (int i=0;i<4;i++)
#pragma unroll
        for (int r=0;r<4;r++) rs[i][r] += __shfl_xor(rs[i][r], m, 64);
    if (cc == 0) {
      float* T = (mode==0) ? q2 : k2;
#pragma unroll
      for (int i=0;i<4;i++)
#pragma unroll
        for (int r=0;r<4;r++) {
          int rg = m0 + wm + i*16 + rr + r;
          atomicAdd(&T[rg], rs[i][r]);
        }
    }
  }
}

// ---- VP = V @ Mp  (associativity: (P@V)@Mp == P@(V@Mp)); write VP^T f16 ----
__global__ __launch_bounds__(256)
void k_vp(const f16* Vh, const f16* Mt, f16* VPt) {
  __shared__ f16 Asm[2][128*32];
  __shared__ f16 Bsm[2][128*32];
  int t0 = blockIdx.x*128, n0 = blockIdx.y*128, b = blockIdx.z;
  int tid = threadIdx.x;
  int lane = tid & 63, w = tid >> 6;
  int wm = (w>>1)*64, wn = (w&1)*64;
  const f16* Ag = Mt + 3*65536 + n0*256;               // rows = n, stride 256
  const f16* Bg = Vh + ((size_t)(b*S_LEN) + t0)*256;   // rows = t, stride 256
  f32x4 acc[4][4] = {};
  stage16(Asm[0], Ag, 256, tid);
  stage16(Bsm[0], Bg, 256, tid);
  __syncthreads();
  for (int kb=0;kb<8;kb++) {
    int cur = kb & 1;
    if (kb < 7) {
      stage16(Asm[cur^1], Ag + (kb+1)*32, 256, tid);
      stage16(Bsm[cur^1], Bg + (kb+1)*32, 256, tid);
    }
    mfma_step(Asm[cur], Bsm[cur], lane, wm, wn, acc);
    __syncthreads();
  }
  int rr = (lane>>4)*4, cc = lane & 15;
#pragma unroll
  for (int i=0;i<4;i++) {
    int n = n0 + wm + i*16 + rr;
#pragma unroll
    for (int j=0;j<4;j++) {
      int t = t0 + wn + j*16 + cc;
#pragma unroll
      for (int r=0;r<4;r++)
        VPt[(size_t)b*1048576 + (size_t)(n + r)*4096 + t] = (f16)acc[i][j][r];
    }
  }
}

// ---- QK pass, lower-triangle tiles only: double-buffered GEMM, P tile staged
//      through LDS and stored COALESCED (f16x8); atomic lsum ----
__global__ __launch_bounds__(256)
void k_attn(const f16* Qh, const f16* Kh, const float* q2, const float* k2,
            const float* sc, float* lsum, f16* Pws) {
  __shared__ f16 smem[4*128*32];     // staging dbuf (32 KB), reused as P tile
  __shared__ float q2s[128], k2s[128];
  f16* Asm0 = smem;
  f16* Asm1 = smem + 4096;
  f16* Bsm0 = smem + 8192;
  f16* Bsm1 = smem + 12288;
  int x = blockIdx.x;
  int b = x >= 528; int r = x - b*528;
  int sb = 0; while (r > sb) { r -= sb + 1; sb++; }
  int tb = r;
  int s0 = sb*128, t0 = tb*128;
  int tid = threadIdx.x;
  if (tid < 128) {
    q2s[tid] = q2[b*S_LEN + s0 + tid];
    k2s[tid] = k2[b*S_LEN + t0 + tid];
  }
  float kc = sc[0], nf2 = sc[1];
  int lane = tid & 63, w = tid >> 6;
  int wm = (w >> 1)*64, wn = (w & 1)*64;
  const f16* Ag = Qh + ((size_t)(b*S_LEN) + s0)*256;
  const f16* Bg = Kh + ((size_t)(b*S_LEN) + t0)*256;
  f32x4 acc[4][4] = {};
  stage16(Asm0, Ag, 256, tid);
  stage16(Bsm0, Bg, 256, tid);
  __syncthreads();
  for (int kb=0;kb<8;kb++) {
    int cur = kb & 1;
    if (kb < 7) {
      stage16(cur ? Asm0 : Asm1, Ag + (kb+1)*32, 256, tid);
      stage16(cur ? Bsm0 : Bsm1, Bg + (kb+1)*32, 256, tid);
    }
    mfma_step(cur ? Asm1 : Asm0, cur ? Bsm1 : Bsm0, lane, wm, wn, acc);
    __syncthreads();
  }
  // P in registers -> LDS tile (staging space now free) -> coalesced stores
  f16* Psm = smem;                   // [128][128] f16 = 32 KB
  int rr = (lane>>4)*4, cc = lane & 15;
  bool diag = (tb == sb);
  float rs[4][4];
#pragma unroll
  for (int i=0;i<4;i++)
#pragma unroll
    for (int rg=0;rg<4;rg++) rs[i][rg]=0.f;
#pragma unroll
  for (int i=0;i<4;i++)
#pragma unroll
    for (int j=0;j<4;j++) {
      int cl = wn + j*16 + cc;
      float kv = k2s[cl];
#pragma unroll
      for (int rg=0;rg<4;rg++) {
        int rl = wm + i*16 + rr + rg;
        float xx = nf2 + q2s[rl] + kv - 2.0f*acc[i][j][rg];
        float P = __builtin_exp2f(kc * __builtin_log2f(__builtin_fmaxf(xx, 1e-6f)));
        if (diag && (t0+cl) > (s0+rl)) P = 0.f;
        Psm[rl*128 + cl] = (f16)P;
        rs[i][rg] += P;
      }
    }
  __syncthreads();
  // coalesced store: 16 consecutive threads cover one 256B row
  f16* Pg = Pws + ((size_t)(b*S_LEN) + s0)*S_LEN + t0;
#pragma unroll
  for (int i2 = 0; i2 < 8; ++i2) {
    int idx = i2*256 + tid;
    int row = idx >> 4, c = idx & 15;
    *(f16x8*)(Pg + (size_t)row*S_LEN + c*8) = *(const f16x8*)(Psm + row*128 + c*8);
  }
#pragma unroll
  for (int m=8;m>=1;m>>=1)
#pragma unroll
    for (int i=0;i<4;i++)
#pragma unroll
      for (int rg=0;rg<4;rg++) rs[i][rg] += __shfl_xor(rs[i][rg], m, 64);
  if (cc == 0)
#pragma unroll
    for (int i=0;i<4;i++)
#pragma unroll
      for (int rg=0;rg<4;rg++) {
        int rl = wm + i*16 + rr + rg;
        atomicAdd(&lsum[b*S_LEN + s0 + rl], rs[i][rg]);
      }
}

// ---- norm: stream Pws f16 -> normalized fp32 attn, lower tiles only.
//      Pure BW kernel: 256B reads / 512B writes per 32-lane group ----
__global__ __launch_bounds__(256)
void k_norm(const f16* Pws, const float* lsum, float* attn) {
  __shared__ float ls[128];
  int x = blockIdx.x;
  int b = x >= 528; int r = x - b*528;
  int sb = 0; while (r > sb) { r -= sb + 1; sb++; }
  int tb = r;
  int s0 = sb*128, t0 = tb*128;
  int tid = threadIdx.x;
  if (tid < 128) ls[tid] = 1.0f / lsum[b*S_LEN + s0 + tid];
  __syncthreads();
  const f16* Pg = Pws + ((size_t)(b*S_LEN) + s0)*S_LEN + t0;
  float* Ag = attn + ((size_t)(b*S_LEN) + s0)*S_LEN + t0;
#pragma unroll
  for (int it = 0; it < 16; ++it) {
    int idx = it*256 + tid;
    int row = idx >> 5, c4 = idx & 31;       // c4: float4 column group
    f16x4 v = *(const f16x4*)(Pg + (size_t)row*S_LEN + c4*4);
    float invl = ls[row];
    float4 o;
    o.x=(float)v[0]*invl; o.y=(float)v[1]*invl;
    o.z=(float)v[2]*invl; o.w=(float)v[3]*invl;
    *(float4*)(Ag + (size_t)row*S_LEN + c4*4) = o;
  }
}

// ---- PV: out += (P @ VPt^T) * 1/l -- pure GEMM, uniform 4-tile chunks,
//      fp32 atomics into the bias-prefilled output ----
__global__ __launch_bounds__(256)
void k_pv(const f16* Pws, const f16* VPt, const float* lsum, float* outp) {
  __shared__ f16 Asm[2][128*32];
  __shared__ f16 Bsm[2][128*32];
  __shared__ float ls[128];
  int r = blockIdx.x;                 // 0..143 -> (sb, chunk)
  int nb = blockIdx.y, b = blockIdx.z;
  int sb = 0;
  while (r >= ((sb+4)>>2)) { r -= (sb+4)>>2; sb++; }
  int c = r;
  int s0 = sb*128, h0 = nb*128;
  int tid = threadIdx.x;
  if (tid < 128) ls[tid] = 1.0f / lsum[b*S_LEN + s0 + tid];
  int lane = tid & 63, w = tid >> 6;
  int wm = (w>>1)*64, wn = (w&1)*64;
  int tb0 = c*4, tb1 = tb0 + 4; if (tb1 > sb+1) tb1 = sb+1;
  int nt = (tb1 - tb0) * 4;
  int base_t = tb0*128;
  const f16* Abase = Pws + ((size_t)(b*S_LEN) + s0)*S_LEN + base_t;
  const f16* Bbase = VPt + (size_t)b*1048576 + (size_t)h0*4096 + base_t;
  f32x4 acc[4][4] = {};
  stage16(Asm[0], Abase, S_LEN, tid);
  stage16(Bsm[0], Bbase, 4096, tid);
  __syncthreads();
  for (int st = 0; st < nt; ++st) {
    int cur = st & 1;
    if (st + 1 < nt) {
      stage16(Asm[cur^1], Abase + (st+1)*32, S_LEN, tid);
      stage16(Bsm[cur^1], Bbase + (st+1)*32, 4096, tid);
    }
    mfma_step(Asm[cur], Bsm[cur], lane, wm, wn, acc);
    __syncthreads();
  }
  int rr = (lane>>4)*4, cc = lane & 15;
#pragma unroll
  for (int i=0;i<4;i++)
#pragma unroll
    for (int j=0;j<4;j++) {
      int cg = h0 + wn + j*16 + cc;
      int comp = cg >> 7, h = cg & 127;
#pragma unroll
      for (int rg=0;rg<4;rg++) {
        int rl = wm + i*16 + rr + rg;
        float v = acc[i][j][rg] * ls[rl];
        atomicAdd(&outp[(((size_t)(b*2 + comp))*S_LEN + s0 + rl)*128 + h], v);
      }
    }
}

extern "C" void kernel_launch(void* const* d_in, const int* in_sizes, int n_in,
                              void* d_out, int out_size, void* d_ws, size_t ws_size,
                              hipStream_t stream) {
  (void)in_sizes; (void)n_in; (void)out_size;
  if (ws_size < (size_t)WS_NEED) return;  // fail loudly (output stays poisoned)
  const float* Zq = (const float*)d_in[0];
  const float* Zk = (const float*)d_in[1];
  const float* Zv = (const float*)d_in[2];
  char* ws = (char*)d_ws;
  f16*   Mt   = (f16*)(ws + MT_OFF);
  float* bias = (float*)(ws + BIAS_OFF);
  float* sc   = (float*)(ws + SC_OFF);
  f16*   Qh   = (f16*)(ws + QH_OFF);
  f16*   Kh   = (f16*)(ws + KH_OFF);
  f16*   Vh   = (f16*)(ws + VH_OFF);
  float* q2   = (float*)(ws + Q2_OFF);
  float* k2   = (float*)(ws + K2_OFF);
  float* lsum = (float*)(ws + L_OFF);
  f16*   VPt  = (f16*)(ws + VPT_OFF);
  f16*   Pws  = (f16*)(ws + PW_OFF);
  float* outp = (float*)d_out;
  float* attn = outp + OUT_ELEMS;

  k_build<<<dim3(4,256), 256, 0, stream>>>(
      (const float*)d_in[3],  (const float*)d_in[4],  (const float*)d_in[5],  (const float*)d_in[6],
      (const float*)d_in[7],  (const float*)d_in[8],  (const float*)d_in[9],  (const float*)d_in[10],
      (const float*)d_in[11], (const float*)d_in[12], (const float*)d_in[13], (const float*)d_in[14],
      (const float*)d_in[15], (const float*)d_in[16], (const float*)d_in[17], (const float*)d_in[18],
      Mt, bias);
  k_init<<<3088, 256, 0, stream>>>(outp, attn, q2, sc, bias,
                                   (const float*)d_in[19], (const float*)d_in[20]);
  k_proj<<<dim3(64,2,3), 256, 0, stream>>>(Zq, Zk, Zv, Mt, bias, Qh, Kh, Vh, q2, k2);
  k_vp<<<dim3(32,2,2), 256, 0, stream>>>(Vh, Mt, VPt);
  k_attn<<<1056, 256, 0, stream>>>(Qh, Kh, q2, k2, sc, lsum, Pws);
  k_norm<<<1056, 256, 0, stream>>>(Pws, lsum, attn);
  k_pv<<<dim3(144,2,2), 256, 0, stream>>>(Pws, VPt, lsum, outp);
}

// Round 6
// 303.242 us; speedup vs baseline: 1.0446x; 1.0446x over previous
//
#include <hip/hip_runtime.h>

#define S_LEN 4096
#define OUT_ELEMS 2097152            // B*2*S*H

typedef _Float16 f16;
typedef _Float16 f16x8 __attribute__((ext_vector_type(8)));
typedef _Float16 f16x4 __attribute__((ext_vector_type(4)));
typedef float f32x4 __attribute__((ext_vector_type(4)));

// ---- workspace layout (bytes) ----
#define MT_OFF    0x000000   // 4 x 256x256 f16 (transposed M matrices)  512 KB
#define BIAS_OFF  0x080000   // 4 x 256 f32
#define SC_OFF    0x081000   // scalars: kc, nf2
#define BVP_OFF   0x082000   // 256 f32 = bv @ Mp
#define W2_OFF    0x090000   // 256x256 f16 = (Mv@Mp) transposed  128 KB
#define QH_OFF    0x100000   // 8192x256 f16   4 MB
#define KH_OFF    0x500000   // 8192x256 f16   4 MB
#define Q2_OFF    0xD00000   // 8192 f32 (q2, k2, lsum share a 192KB zeroed region)
#define K2_OFF    0xD10000
#define L_OFF     0xD20000
#define VPT_OFF   0xE00000   // [b][256][4096] f16 = (V@Mp)^T (incl bvp)   4 MB
#define PW_OFF    0x1600000  // [b][4096][4096] f16 unnormalized P   64 MB
#define WS_NEED   0x5600000

#define MFMA16(A,B,C) __builtin_amdgcn_mfma_f32_16x16x32_f16(A,B,C,0,0,0)

__device__ __forceinline__ void async_cp16(f16* lds, const f16* g) {
  __builtin_amdgcn_global_load_lds(
      (const __attribute__((address_space(1))) void*)g,
      (__attribute__((address_space(3))) void*)lds, 16, 0, 0);
}

// T2 swizzle: logical 16B-chunk s of row r lives at LDS chunk s ^ ((r>>1)&3).
// DMA dest stays linear (global_load_lds requirement); the global SOURCE is
// pre-permuted; LDS reads apply the same XOR.

// stage 128x32 f16 tile (global row stride = stride elems) -> lds[128][32] swizzled
__device__ __forceinline__ void stage16(f16* lds, const f16* g, int stride, int tid) {
#pragma unroll
  for (int i = 0; i < 2; ++i) {
    int idx = i*256 + tid;
    int row = idx >> 2, c = idx & 3;
    int cs = c ^ ((row >> 1) & 3);
    async_cp16(lds + idx*8, g + (size_t)row*stride + cs*8);
  }
}

// stage 128x32 f32 tile -> f16 lds[128][32] (convert), swizzled LDS write
__device__ __forceinline__ void stage32(f16* lds, const float* g, int stride, int tid) {
#pragma unroll
  for (int i = 0; i < 4; ++i) {
    int idx = i*256 + tid;
    int row = idx >> 3, c = idx & 7;           // c: 8B units
    const float4* gp = (const float4*)(g + (size_t)row*stride + c*4);
    float4 v = *gp;
    f16x4 h; h[0]=(f16)v.x; h[1]=(f16)v.y; h[2]=(f16)v.z; h[3]=(f16)v.w;
    int cl = (((c >> 1) ^ ((row >> 1) & 3)) << 1) | (c & 1);
    *(f16x4*)(lds + row*32 + cl*4) = h;
  }
}

// one BK=32 step: 4 A-frags, 4 B-frags, 16 MFMAs (wave covers 64x64)
__device__ __forceinline__ void mfma_step(const f16* Asm, const f16* Bsm, int lane,
                                          int wm, int wn, f32x4 acc[4][4]) {
  f16x8 a[4], b[4];
  int rr = lane & 15;
  int sc = (lane >> 4) ^ ((rr >> 1) & 3);   // swizzled 16B chunk index
#pragma unroll
  for (int i=0;i<4;i++) a[i] = *(const f16x8*)(Asm + (wm + i*16 + rr)*32 + (sc<<3));
#pragma unroll
  for (int j=0;j<4;j++) b[j] = *(const f16x8*)(Bsm + (wn + j*16 + rr)*32 + (sc<<3));
#pragma unroll
  for (int i=0;i<4;i++)
#pragma unroll
    for (int j=0;j<4;j++) acc[i][j] = MFMA16(a[i], b[j], acc[i][j]);
}

// ---- build combined complex-linear matrices Mt[n][k] = M[k][n], and biases ----
__global__ __launch_bounds__(256)
void k_build(const float* Wqr, const float* Wqi, const float* bqr, const float* bqi,
             const float* Wkr, const float* Wki, const float* bkr, const float* bki,
             const float* Wvr, const float* Wvi, const float* bvr, const float* bvi,
             const float* Wpr, const float* Wpi, const float* bpr, const float* bpi,
             f16* Mt, float* bias) {
  int mat = blockIdx.x;
  const float *Wr, *Wi, *br, *bi;
  if (mat == 0)      { Wr=Wqr; Wi=Wqi; br=bqr; bi=bqi; }
  else if (mat == 1) { Wr=Wkr; Wi=Wki; br=bkr; bi=bki; }
  else if (mat == 2) { Wr=Wvr; Wi=Wvi; br=bvr; bi=bvi; }
  else               { Wr=Wpr; Wi=Wpi; br=bpr; bi=bpi; }
  int idx = blockIdx.y*256 + threadIdx.x;
  int n = idx >> 8, k = idx & 255;
  int d = k & 127, h = n & 127;
  float w = (k < 128) ? ((n < 128) ? Wr[h*128+d] : Wi[h*128+d])
                      : ((n < 128) ? -Wi[h*128+d] : Wr[h*128+d]);
  Mt[mat*65536 + n*256 + k] = (f16)w;
  if (k == 0)
    bias[mat*256 + n] = (n < 128) ? (br[n] - bi[n]) : (br[n-128] + bi[n-128]);
}

// ---- W2 = Mv @ Mp (f16 inputs, fp32 accum), stored transposed like Mt;
//      bvp = bv @ Mp ----
__global__ __launch_bounds__(256)
void k_build2(const f16* Mt, const float* bias, f16* W2t, float* bvp) {
  int n = blockIdx.x, k = threadIdx.x;
  const f16* Mtv = Mt + 2*65536;    // Mtv[j][k] = Mv[k][j]
  const f16* Mtp = Mt + 3*65536;    // Mtp[n][j] = Mp[j][n]
  float acc = 0.f;
  for (int j = 0; j < 256; ++j)
    acc += (float)Mtv[j*256 + k] * (float)Mtp[n*256 + j];
  W2t[n*256 + k] = (f16)acc;        // W2t[n][k] = W2[k][n] = (Mv@Mp)[k][n]
  if (k == 0) {
    float a = 0.f;
    for (int j = 0; j < 256; ++j) a += bias[2*256 + j] * (float)Mtp[n*256 + j];
    bvp[n] = a;
  }
}

// ---- init: coalesced zero of strictly-upper attn tiles (992 blocks);
//      prefill out with bias; zero q2/k2/lsum; compute scalars ----
__global__ __launch_bounds__(256)
void k_init(float* outp, float* attn, float* zreg, float* sc, const float* bias,
            const float* nf, const float* tau) {
  int bx = blockIdx.x, tid = threadIdx.x;
  float4 z = make_float4(0.f,0.f,0.f,0.f);
  if (bx < 992) {              // one strictly-upper 128x128 tile, coalesced
    int b = bx >= 496; int r = bx - b*496;
    int tb = 1; while (r >= tb) { r -= tb; tb++; }
    int sb = r;
    float* base = attn + ((size_t)(b*S_LEN) + sb*128)*S_LEN + tb*128;
    int c4 = tid & 31;
#pragma unroll
    for (int it = 0; it < 16; ++it) {
      int row = it*8 + (tid >> 5);
      *(float4*)(base + (size_t)row*S_LEN + c4*4) = z;
    }
    return;
  }
  int idx = (bx - 992)*256 + tid;
  if (idx < 524288) {          // out prefill with bias
    int h4 = idx & 31;
    int comp = (idx >> 17) & 1;
    ((float4*)outp)[idx] = *(const float4*)(bias + 3*256 + comp*128 + h4*4);
  } else {
    int j = idx - 524288;
    if (j < 12288) ((float4*)zreg)[j] = z;
  }
  if (idx == 0) {
    float t = tau[0];
    float c = __builtin_log2f(1.0f + __builtin_exp2f(t * 1.4426950408889634f))
              * 0.6931471805599453f;        // softplus(tau)
    sc[0] = -c * 0.08838834764831845f;       // kc = -softplus(tau)/sqrt(128)
    sc[1] = nf[0]*nf[0] + 1e-6f;             // nf^2 + EPS
  }
}

// ---- projections. mode 0/1: Q/K + fused |row|^2, coalesced f16x8 stores via
//      LDS roundtrip. mode 2: VPt = Zv@W2 + bvp, transposed store via padded
//      LDS roundtrip (coalesced along t). ----
__global__ __launch_bounds__(256)
void k_proj(const float* Zq, const float* Zk, const float* Zv,
            const f16* Mt, const f16* W2t, const float* bias, const float* bvp,
            f16* Qh, f16* Kh, f16* VPt, float* q2, float* k2) {
  __shared__ f16 smem[17408];        // staging dbuf (32KB) / Osm [128][136]
  __shared__ float bias_s[128];
  f16* A0 = smem;
  f16* A1 = smem + 4096;
  f16* B0 = smem + 8192;
  f16* B1 = smem + 12288;
  int tid = threadIdx.x;
  int mode = blockIdx.z;
  int m0 = blockIdx.x * 128, n0 = blockIdx.y * 128;
  const float* Z = (mode==0) ? Zq : (mode==1 ? Zk : Zv);
  const f16* Bt = (mode==2) ? W2t : (Mt + mode*65536);
  if (tid < 128) bias_s[tid] = (mode==2) ? bvp[n0 + tid] : bias[mode*256 + n0 + tid];
  int b = m0 >> 12, s0 = m0 & 4095;
  int lane = tid & 63, w = tid >> 6;
  int wm = (w >> 1)*64, wn = (w & 1)*64;
  f32x4 acc[4][4] = {};
  {
    const float* Ag = Z + (((size_t)(b*2 + 0))*S_LEN + s0)*128 + 0;
    stage32(A0, Ag, 128, tid);
    stage16(B0, Bt + n0*256 + 0, 256, tid);
  }
  __syncthreads();
  for (int kb = 0; kb < 8; ++kb) {
    int cur = kb & 1;
    if (kb < 7) {
      int k1 = (kb+1)*32;
      int part = k1 >> 7, d0 = k1 & 127;
      const float* Ag = Z + (((size_t)(b*2 + part))*S_LEN + s0)*128 + d0;
      stage32(cur ? A0 : A1, Ag, 128, tid);
      stage16(cur ? B0 : B1, Bt + n0*256 + k1, 256, tid);
    }
    mfma_step(cur ? A1 : A0, cur ? B1 : B0, lane, wm, wn, acc);
    __syncthreads();
  }
  int rr2 = (lane>>4)*4, cc = lane & 15;
  f16* Osm = smem;                   // [128][136] f16 (pad keeps 16B-aligned rows)
  float rs[4][4];
#pragma unroll
  for (int i=0;i<4;i++)
#pragma unroll
    for (int r=0;r<4;r++) rs[i][r]=0.f;
  if (mode < 2) {
#pragma unroll
    for (int i=0;i<4;i++)
#pragma unroll
      for (int j=0;j<4;j++) {
        int cl = wn + j*16 + cc;
        float bv = bias_s[cl];
#pragma unroll
        for (int r=0;r<4;r++) {
          int rl = wm + i*16 + rr2 + r;
          f16 hv = (f16)(acc[i][j][r] + bv);
          Osm[rl*136 + cl] = hv;
          float fv = (float)hv;
          rs[i][r] += fv*fv;
        }
      }
  } else {
#pragma unroll
    for (int i=0;i<4;i++)
#pragma unroll
      for (int j=0;j<4;j++) {
        int cl = wn + j*16 + cc;
        float bv = bias_s[cl];
#pragma unroll
        for (int r=0;r<4;r++) {
          int rl = wm + i*16 + rr2 + r;
          Osm[cl*136 + rl] = (f16)(acc[i][j][r] + bv);   // transposed: [n][t]
        }
      }
  }
  __syncthreads();
  if (mode < 2) {
    f16* O = (mode==0) ? Qh : Kh;
#pragma unroll
    for (int i2 = 0; i2 < 8; ++i2) {
      int idx = i2*256 + tid;
      int row = idx >> 4, c = idx & 15;
      *(f16x8*)(O + (size_t)(m0+row)*256 + n0 + c*8) = *(const f16x8*)(Osm + row*136 + c*8);
    }
#pragma unroll
    for (int m=8;m>=1;m>>=1)
#pragma unroll
      for (int i=0;i<4;i++)
#pragma unroll
        for (int r=0;r<4;r++) rs[i][r] += __shfl_xor(rs[i][r], m, 64);
    if (cc == 0) {
      float* T = (mode==0) ? q2 : k2;
#pragma unroll
      for (int i=0;i<4;i++)
#pragma unroll
        for (int r=0;r<4;r++) {
          int rg = m0 + wm + i*16 + rr2 + r;
          atomicAdd(&T[rg], rs[i][r]);
        }
    }
  } else {
    // rows = n-local, cols = t (coalesced along t)
#pragma unroll
    for (int i2 = 0; i2 < 8; ++i2) {
      int idx = i2*256 + tid;
      int row = idx >> 4, c = idx & 15;
      *(f16x8*)(VPt + (size_t)b*1048576 + (size_t)(n0+row)*4096 + s0 + c*8)
          = *(const f16x8*)(Osm + row*136 + c*8);
    }
  }
}

// ---- QK pass, lower-triangle tiles only: double-buffered GEMM, P tile staged
//      through LDS and stored COALESCED (f16x8); atomic lsum ----
__global__ __launch_bounds__(256)
void k_attn(const f16* Qh, const f16* Kh, const float* q2, const float* k2,
            const float* sc, float* lsum, f16* Pws) {
  __shared__ f16 smem[4*128*32];     // staging dbuf (32 KB), reused as P tile
  __shared__ float q2s[128], k2s[128];
  f16* Asm0 = smem;
  f16* Asm1 = smem + 4096;
  f16* Bsm0 = smem + 8192;
  f16* Bsm1 = smem + 12288;
  int x = blockIdx.x;
  int b = x >= 528; int r = x - b*528;
  int sb = 0; while (r > sb) { r -= sb + 1; sb++; }
  int tb = r;
  int s0 = sb*128, t0 = tb*128;
  int tid = threadIdx.x;
  if (tid < 128) {
    q2s[tid] = q2[b*S_LEN + s0 + tid];
    k2s[tid] = k2[b*S_LEN + t0 + tid];
  }
  float kc = sc[0], nf2 = sc[1];
  int lane = tid & 63, w = tid >> 6;
  int wm = (w >> 1)*64, wn = (w & 1)*64;
  const f16* Ag = Qh + ((size_t)(b*S_LEN) + s0)*256;
  const f16* Bg = Kh + ((size_t)(b*S_LEN) + t0)*256;
  f32x4 acc[4][4] = {};
  stage16(Asm0, Ag, 256, tid);
  stage16(Bsm0, Bg, 256, tid);
  __syncthreads();
  for (int kb=0;kb<8;kb++) {
    int cur = kb & 1;
    if (kb < 7) {
      stage16(cur ? Asm0 : Asm1, Ag + (kb+1)*32, 256, tid);
      stage16(cur ? Bsm0 : Bsm1, Bg + (kb+1)*32, 256, tid);
    }
    mfma_step(cur ? Asm1 : Asm0, cur ? Bsm1 : Bsm0, lane, wm, wn, acc);
    __syncthreads();
  }
  f16* Psm = smem;                   // [128][128] f16 = 32 KB
  int rr = (lane>>4)*4, cc = lane & 15;
  bool diag = (tb == sb);
  float rs[4][4];
#pragma unroll
  for (int i=0;i<4;i++)
#pragma unroll
    for (int rg=0;rg<4;rg++) rs[i][rg]=0.f;
#pragma unroll
  for (int i=0;i<4;i++)
#pragma unroll
    for (int j=0;j<4;j++) {
      int cl = wn + j*16 + cc;
      float kv = k2s[cl];
#pragma unroll
      for (int rg=0;rg<4;rg++) {
        int rl = wm + i*16 + rr + rg;
        float xx = nf2 + q2s[rl] + kv - 2.0f*acc[i][j][rg];
        float P = __builtin_exp2f(kc * __builtin_log2f(__builtin_fmaxf(xx, 1e-6f)));
        if (diag && (t0+cl) > (s0+rl)) P = 0.f;
        Psm[rl*128 + cl] = (f16)P;
        rs[i][rg] += P;
      }
    }
  __syncthreads();
  f16* Pg = Pws + ((size_t)(b*S_LEN) + s0)*S_LEN + t0;
#pragma unroll
  for (int i2 = 0; i2 < 8; ++i2) {
    int idx = i2*256 + tid;
    int row = idx >> 4, c = idx & 15;
    *(f16x8*)(Pg + (size_t)row*S_LEN + c*8) = *(const f16x8*)(Psm + row*128 + c*8);
  }
#pragma unroll
  for (int m=8;m>=1;m>>=1)
#pragma unroll
    for (int i=0;i<4;i++)
#pragma unroll
      for (int rg=0;rg<4;rg++) rs[i][rg] += __shfl_xor(rs[i][rg], m, 64);
  if (cc == 0)
#pragma unroll
    for (int i=0;i<4;i++)
#pragma unroll
      for (int rg=0;rg<4;rg++) {
        int rl = wm + i*16 + rr + rg;
        atomicAdd(&lsum[b*S_LEN + s0 + rl], rs[i][rg]);
      }
}

// ---- PV v2: 512 threads, 128s x 256h per block (h-halves merged -> P read
//      once), normalized attn written in-loop from staged P, atomics into
//      bias-prefilled out ----
__global__ __launch_bounds__(512)
void k_pv(const f16* Pws, const f16* VPt, const float* lsum, float* outp, float* attn) {
  __shared__ f16 Asm[2][128*32];     // P tiles (8 KB each)
  __shared__ f16 Bsm[2][256*32];     // VPt tiles (16 KB each)
  __shared__ float ls[128];
  int r = blockIdx.x, b = blockIdx.y;
  int sb = 0;
  while (r >= ((sb+4)>>2)) { r -= (sb+4)>>2; sb++; }
  int c = r;
  int s0 = sb*128;
  int tid = threadIdx.x;
  if (tid < 128) ls[tid] = 1.0f / lsum[b*S_LEN + s0 + tid];
  int lane = tid & 63, w = tid >> 6;
  int wm = (w>>2)*64, wn = (w&3)*64;
  int tb0 = c*4, tb1 = tb0 + 4; if (tb1 > sb+1) tb1 = sb+1;
  int nt = (tb1 - tb0) * 4;
  int base_t = tb0*128;
  const f16* Abase = Pws + ((size_t)(b*S_LEN) + s0)*S_LEN + base_t;
  const f16* Bbase = VPt + (size_t)b*1048576 + base_t;
  f32x4 acc[4][4] = {};
  // prologue: stage step 0
  {
    int row = tid >> 2, cc0 = tid & 3, cs = cc0 ^ ((row >> 1) & 3);
    async_cp16(Asm[0] + tid*8, Abase + (size_t)row*S_LEN + cs*8);
  }
#pragma unroll
  for (int i=0;i<2;i++) {
    int idx = i*512 + tid, row = idx >> 2, cc0 = idx & 3, cs = cc0 ^ ((row >> 1) & 3);
    async_cp16(Bsm[0] + idx*8, Bbase + (size_t)row*4096 + cs*8);
  }
  __syncthreads();
  for (int st = 0; st < nt; ++st) {
    int cur = st & 1;
    int tcur = base_t + st*32;
    if (st + 1 < nt) {
      const f16* Ag = Abase + (st+1)*32;
      const f16* Bg = Bbase + (st+1)*32;
      {
        int row = tid >> 2, cc0 = tid & 3, cs = cc0 ^ ((row >> 1) & 3);
        async_cp16(Asm[cur^1] + tid*8, Ag + (size_t)row*S_LEN + cs*8);
      }
#pragma unroll
      for (int i=0;i<2;i++) {
        int idx = i*512 + tid, row = idx >> 2, cc0 = idx & 3, cs = cc0 ^ ((row >> 1) & 3);
        async_cp16(Bsm[cur^1] + idx*8, Bg + (size_t)row*4096 + cs*8);
      }
    }
    // normalized attn slab [128][32] fp32, coalesced
#pragma unroll
    for (int i2=0;i2<2;i2++) {
      int idx = i2*512 + tid, row = idx >> 3, c4 = idx & 7;
      int cs = (c4 >> 1) ^ ((row >> 1) & 3);
      f16x4 v = *(const f16x4*)(Asm[cur] + row*32 + cs*8 + (c4 & 1)*4);
      float invl = ls[row];
      float4 o;
      o.x=(float)v[0]*invl; o.y=(float)v[1]*invl;
      o.z=(float)v[2]*invl; o.w=(float)v[3]*invl;
      *(float4*)(attn + ((size_t)(b*S_LEN) + s0 + row)*S_LEN + tcur + c4*4) = o;
    }
    mfma_step(Asm[cur], Bsm[cur], lane, wm, wn, acc);
    __syncthreads();
  }
  int rr2 = (lane>>4)*4, cc = lane & 15;
#pragma unroll
  for (int i=0;i<4;i++)
#pragma unroll
    for (int j=0;j<4;j++) {
      int cg = wn + j*16 + cc;
      int comp = cg >> 7, h = cg & 127;
#pragma unroll
      for (int rg=0;rg<4;rg++) {
        int rl = wm + i*16 + rr2 + rg;
        float v = acc[i][j][rg] * ls[rl];
        atomicAdd(&outp[(((size_t)(b*2 + comp))*S_LEN + s0 + rl)*128 + h], v);
      }
    }
}

extern "C" void kernel_launch(void* const* d_in, const int* in_sizes, int n_in,
                              void* d_out, int out_size, void* d_ws, size_t ws_size,
                              hipStream_t stream) {
  (void)in_sizes; (void)n_in; (void)out_size;
  if (ws_size < (size_t)WS_NEED) return;  // fail loudly (output stays poisoned)
  const float* Zq = (const float*)d_in[0];
  const float* Zk = (const float*)d_in[1];
  const float* Zv = (const float*)d_in[2];
  char* ws = (char*)d_ws;
  f16*   Mt   = (f16*)(ws + MT_OFF);
  float* bias = (float*)(ws + BIAS_OFF);
  float* sc   = (float*)(ws + SC_OFF);
  float* bvp  = (float*)(ws + BVP_OFF);
  f16*   W2t  = (f16*)(ws + W2_OFF);
  f16*   Qh   = (f16*)(ws + QH_OFF);
  f16*   Kh   = (f16*)(ws + KH_OFF);
  float* q2   = (float*)(ws + Q2_OFF);
  float* k2   = (float*)(ws + K2_OFF);
  float* lsum = (float*)(ws + L_OFF);
  f16*   VPt  = (f16*)(ws + VPT_OFF);
  f16*   Pws  = (f16*)(ws + PW_OFF);
  float* outp = (float*)d_out;
  float* attn = outp + OUT_ELEMS;

  k_build<<<dim3(4,256), 256, 0, stream>>>(
      (const float*)d_in[3],  (const float*)d_in[4],  (const float*)d_in[5],  (const float*)d_in[6],
      (const float*)d_in[7],  (const float*)d_in[8],  (const float*)d_in[9],  (const float*)d_in[10],
      (const float*)d_in[11], (const float*)d_in[12], (const float*)d_in[13], (const float*)d_in[14],
      (const float*)d_in[15], (const float*)d_in[16], (const float*)d_in[17], (const float*)d_in[18],
      Mt, bias);
  k_build2<<<256, 256, 0, stream>>>(Mt, bias, W2t, bvp);
  k_init<<<3088, 256, 0, stream>>>(outp, attn, q2, sc, bias,
                                   (const float*)d_in[19], (const float*)d_in[20]);
  k_proj<<<dim3(64,2,3), 256, 0, stream>>>(Zq, Zk, Zv, Mt, W2t, bias, bvp,
                                           Qh, Kh, VPt, q2, k2);
  k_attn<<<1056, 256, 0, stream>>>(Qh, Kh, q2, k2, sc, lsum, Pws);
  k_pv<<<dim3(144,2), 512, 0, stream>>>(Pws, VPt, lsum, outp, attn);
}